// Round 3
// baseline (696.913 us; speedup 1.0000x reference)
//
#include <hip/hip_runtime.h>
#include <hip/hip_bf16.h>
#include <stdint.h>
#include <stddef.h>

// Inputs/outputs are fp32. Weights are converted once to bf16 in ws; GEMMs run
// bf16 MFMA with fp32 accumulate.
// R3 changes vs R2 (662 us):
//  - NEW gemm256: 256x256 tile, 512 thr (8 waves, 2Mx4N, wave=128x64 out),
//    K-step 32, double-buffered 64 KiB LDS, XOR swizzle cb^=(row>>1)&3 (2-way
//    minimum on ds_read_b128). Halves VMEM+LDS traffic per FLOP vs 128^2 and
//    doubles per-step compute for latency hiding (guide m228d vs m230: 622 vs
//    682 TF same structure). loadRF issued BEFORE compute (R2 exposed it right
//    before the vmcnt(0) barrier drain), double rf sets, static parity indexing.
//  - Heavy dispatches (MODE5, 2xMODE2, MODE4) use gemm256; small GEMMs (M=1024)
//    and the !big fallback keep the proven 128^2 kernel.

using u16 = unsigned short;
using u32 = unsigned int;

__device__ __forceinline__ float u2f(u16 u) {
  union { unsigned i; float f; } c; c.i = ((unsigned)u) << 16; return c.f;
}
__device__ __forceinline__ u16 f2u(float f) {
  __hip_bfloat16 h = __float2bfloat16(f);          // RNE
  union { __hip_bfloat16 h; u16 u; } c; c.h = h; return c.u;
}
__device__ __forceinline__ u32 pk2(float lo, float hi) {
  __hip_bfloat162 h = __float22bfloat162_rn(make_float2(lo, hi));
  union { __hip_bfloat162 h; u32 u; } c; c.h = h; return c.u;
}
__device__ __forceinline__ float sigm(float x) { return 1.f / (1.f + expf(-x)); }

typedef __attribute__((ext_vector_type(8))) short bfrag;   // 8 bf16 = 4 VGPRs
typedef __attribute__((ext_vector_type(4))) float f32x4;

__device__ __forceinline__ void gl_lds16(const u16* g, u16* l) {
  __builtin_amdgcn_global_load_lds((const __attribute__((address_space(1))) void*)g,
                                   (__attribute__((address_space(3))) void*)l,
                                   16, 0, 0);
}

// ---- batched fp32 -> bf16 weight conversion (17 segments, 1 launch) ----
#define NSEG 17
struct CvtArgs {
  const float* src[NSEG];
  u16* dst[NSEG];
  int cum[NSEG + 1];
};
__global__ __launch_bounds__(256) void cvt_multi(CvtArgs a, int total) {
  int i = blockIdx.x * 256 + threadIdx.x;
  if (i >= total) return;
  int s = 0;
  while (s + 1 < NSEG && i >= a.cum[s + 1]) ++s;
  const int off = i - a.cum[s];
  a.dst[s][off] = f2u(a.src[s][off]);
}

// ============================================================================
// 256x256-tile GEMM: C = epilogue(A @ W^T). 512 threads, 8 waves (2M x 4N),
// wave computes 128x64. K-step 32, double-buffered. K%64==0 assumed (even #steps).
// MODE 2: atomicAdd(pred[row], sum_col relu(acc + bias[col]) * wlo[col])
// MODE 4: outb = bf16(relu(sigm(pred[row]) * acc + bias[col]))
// MODE 5: fused: bx<2 -> MODE0-style (ubuf add) into outb; else W2, bias into outb2
// ============================================================================
template <int MODE, bool A32>
__global__ __launch_bounds__(512, 2)
void gemm256(const void* __restrict__ Av, int lda, size_t abase,
             const u16* __restrict__ W, int ldw, int K,
             const u16* __restrict__ bias,
             const float* __restrict__ ubuf,
             const u16* __restrict__ wlo,
             float* __restrict__ pred,
             u16* __restrict__ outb, int ldc,
             const u16* __restrict__ W2, int ldw2, u16* __restrict__ outb2)
{
  // 2 x (As 256x32 + Bs 256x32) bf16 = 32768 u16 = 64 KiB (static max).
  __shared__ u16 smem[32768];
  u16* const As0 = smem;
  u16* const Bs0 = smem + 8192;
  u16* const As1 = smem + 16384;
  u16* const Bs1 = smem + 24576;

  const int tid  = threadIdx.x;
  const int wave = tid >> 6, lane = tid & 63;
  const int wr = wave >> 2, wc = wave & 3;          // 2M x 4N
  const int quad = lane >> 4, l16 = lane & 15;
  const int swz = (quad ^ ((l16 >> 1) & 3)) << 3;   // frag-read swizzle (rows%16==0 base)

  // T1 bijective XCD swizzle
  const int gx = gridDim.x;
  const int nwg = gx * gridDim.y;
  int flat = blockIdx.y * gx + blockIdx.x;
  if ((nwg & 7) == 0) { const int q = nwg >> 3; flat = (flat & 7) * q + (flat >> 3); }
  const int bx = flat % gx;
  const int by = flat / gx;

  const int row0 = by * 256;
  const bool isM = (MODE != 5) || (bx < 2);
  const int col0 = (MODE == 5 ? (bx & 1) : bx) * 256;
  const u16* Wp  = (MODE == 5 && !isM) ? W2  : W;
  const int ldwp = (MODE == 5 && !isM) ? ldw2 : ldw;

  f32x4 acc[8][4];
#pragma unroll
  for (int i = 0; i < 8; i++)
#pragma unroll
    for (int j = 0; j < 4; j++)
#pragma unroll
      for (int r = 0; r < 4; r++) acc[i][j][r] = 0.f;

  auto stageB = [&](int k0, u16* Bb) {
#pragma unroll
    for (int p = 0; p < 2; p++) {
      const int idx = p * 512 + tid;
      const int row = idx >> 2;
      const int cb  = (idx & 3) ^ ((row >> 1) & 3);
      gl_lds16(Wp + (size_t)(col0 + row) * ldwp + k0 + cb * 8, Bb + idx * 8);
    }
  };
  auto stageA = [&](int k0, u16* Ab) {              // !A32 path
#pragma unroll
    for (int p = 0; p < 2; p++) {
      const int idx = p * 512 + tid;
      const int row = idx >> 2;
      const int cb  = (idx & 3) ^ ((row >> 1) & 3);
      gl_lds16((const u16*)Av + (abase + (size_t)(row0 + row)) * lda + k0 + cb * 8,
               Ab + idx * 8);
    }
  };

  float4 rfa[2][4];                                 // double rf sets, static idx only

#define LOADRF(k0, S) {                                                          \
    const float* p_ = (const float*)Av +                                         \
        (abase + (size_t)(row0 + (tid >> 1))) * lda + (k0) + (tid & 1) * 16;     \
    rfa[S][0] = *(const float4*)p_;      rfa[S][1] = *(const float4*)(p_ + 4);   \
    rfa[S][2] = *(const float4*)(p_ + 8); rfa[S][3] = *(const float4*)(p_ + 12); }

#define WRITEA(S, Ab) {                                                          \
    const int r_ = tid >> 1, h_ = tid & 1;                                       \
    const int sw_ = (r_ >> 1) & 3;                                               \
    uint4 w0_, w1_;                                                              \
    w0_.x = pk2(rfa[S][0].x, rfa[S][0].y); w0_.y = pk2(rfa[S][0].z, rfa[S][0].w);\
    w0_.z = pk2(rfa[S][1].x, rfa[S][1].y); w0_.w = pk2(rfa[S][1].z, rfa[S][1].w);\
    w1_.x = pk2(rfa[S][2].x, rfa[S][2].y); w1_.y = pk2(rfa[S][2].z, rfa[S][2].w);\
    w1_.z = pk2(rfa[S][3].x, rfa[S][3].y); w1_.w = pk2(rfa[S][3].z, rfa[S][3].w);\
    *(uint4*)((Ab) + r_ * 32 + (((2 * h_) ^ sw_) << 3))     = w0_;               \
    *(uint4*)((Ab) + r_ * 32 + (((2 * h_ + 1) ^ sw_) << 3)) = w1_; }

  auto compute = [&](const u16* Ab, const u16* Bb) {
    bfrag af[8], bf[4];
#pragma unroll
    for (int mt = 0; mt < 8; mt++)
      af[mt] = *(const bfrag*)(Ab + wr * 4096 + mt * 512 + l16 * 32 + swz);
#pragma unroll
    for (int nt = 0; nt < 4; nt++)
      bf[nt] = *(const bfrag*)(Bb + wc * 2048 + nt * 512 + l16 * 32 + swz);
#pragma unroll
    for (int mt = 0; mt < 8; mt++)
#pragma unroll
      for (int nt = 0; nt < 4; nt++)
        acc[mt][nt] = __builtin_amdgcn_mfma_f32_16x16x32_bf16(af[mt], bf[nt], acc[mt][nt], 0, 0, 0);
  };

  const int ntile = K >> 5;                          // K-steps of 32 (even)

  // ---- prologue: tile 0 staged; tile 1 raw A in rf set 1 ----
  if constexpr (A32) {
    LOADRF(0, 0);
    WRITEA(0, As0);
    stageB(0, Bs0);
    if (ntile > 1) LOADRF(32, 1);
  } else {
    stageA(0, As0);
    stageB(0, Bs0);
  }
  __syncthreads();

  // ---- 2-phase main loop, unrolled x2 for static rf/buffer parity ----
  for (int t = 0; t < ntile; t += 2) {
    {                                                // even step: cur=0, next=1
      const bool more = (t + 1 < ntile);
      if (more) {
        stageB((t + 1) << 5, Bs1);
        if constexpr (!A32) stageA((t + 1) << 5, As1);
        if constexpr (A32) {
          WRITEA(1, As1);                            // tile t+1 (rf loaded last iter)
          if (t + 2 < ntile) LOADRF((t + 2) << 5, 0);  // BEFORE compute: latency hidden
        }
      }
      compute(As0, Bs0);
      __syncthreads();
    }
    if (t + 1 < ntile) {                             // odd step: cur=1, next=0
      const bool more = (t + 2 < ntile);
      if (more) {
        stageB((t + 2) << 5, Bs0);
        if constexpr (!A32) stageA((t + 2) << 5, As0);
        if constexpr (A32) {
          WRITEA(0, As0);
          if (t + 3 < ntile) LOADRF((t + 3) << 5, 1);
        }
      }
      compute(As1, Bs1);
      __syncthreads();
    }
  }
#undef LOADRF
#undef WRITEA

  // C/D layout (m89/m91): col = lane&15, row = quad*4 + reg
  if constexpr (MODE == 2) {
#pragma unroll
    for (int mt = 0; mt < 8; mt++) {
#pragma unroll
      for (int r = 0; r < 4; r++) {
        const int rg = row0 + wr * 128 + mt * 16 + quad * 4 + r;
        float s = 0.f;
#pragma unroll
        for (int nt = 0; nt < 4; nt++) {
          const int cg = col0 + wc * 64 + nt * 16 + l16;
          float v = acc[mt][nt][r] + u2f(bias[cg]);
          v = fmaxf(v, 0.f);
          s += v * u2f(wlo[cg]);
        }
#pragma unroll
        for (int off = 1; off < 16; off <<= 1) s += __shfl_xor(s, off, 16);
        if (l16 == 0) atomicAdd(pred + rg, s);
      }
    }
  } else {
    // bf16 out via LDS (64 rows x 264 stride per pass), 4 passes
    u16* outp = (MODE == 5 && !isM) ? outb2 : outb;
    u16* tile = smem;
#pragma unroll
    for (int p = 0; p < 4; p++) {
      __syncthreads();                               // prev pass copy done / K-loop done
      if (wr == (p >> 1)) {
        const int mtb = (p & 1) * 4;
#pragma unroll
        for (int mi = 0; mi < 4; mi++) {
          const int mt = mtb + mi;
#pragma unroll
          for (int nt = 0; nt < 4; nt++)
#pragma unroll
            for (int r = 0; r < 4; r++) {
              const int rg = row0 + wr * 128 + mt * 16 + quad * 4 + r;
              const int cg = col0 + wc * 64 + nt * 16 + l16;
              float v = acc[mt][nt][r];
              if (MODE == 5 && isM) {
                const size_t grow = (size_t)rg;      // abase==0 for MODE5 use
                const int urow = (int)(((grow >> 12) << 6) | (grow & 63));
                v += ubuf[(size_t)urow * 512 + cg];
                v = fmaxf(v, 0.f);
              } else if (MODE == 5) {
                v += u2f(bias[cg]);
                v = fmaxf(v, 0.f);
              } else {                               // MODE 4
                v = sigm(pred[rg]) * v + u2f(bias[cg]);
                v = fmaxf(v, 0.f);
              }
              const int lrow = mt * 16 + quad * 4 + r - (p & 1) * 64;  // 0..63
              tile[lrow * 264 + wc * 64 + nt * 16 + l16] = f2u(v);
            }
        }
      }
      __syncthreads();
      const int row = tid >> 3, ch = tid & 7;        // 64 rows x 8 chunks of 64B
      const u16* src = tile + row * 264 + ch * 32;
      u16* dst = outp + (size_t)(row0 + p * 64 + row) * ldc + col0 + ch * 32;
#pragma unroll
      for (int j = 0; j < 4; j++)
        *(uint4*)(dst + j * 8) = *(const uint4*)(src + j * 8);
    }
  }
}

// ============================================================================
// 128x128-tile GEMM (R2-proven) — small GEMMs + !big fallback path.
// ============================================================================
template <int MODE, bool A32>
__global__ __launch_bounds__(256)
void gemm_bt(const void* __restrict__ Av, int lda, size_t abase,
             const u16* __restrict__ W, int ldw, int K,
             const u16* __restrict__ bias,
             const float* __restrict__ ubuf,
             const u16* __restrict__ wlo,
             float* __restrict__ pred,
             u16* __restrict__ outb,
             float* __restrict__ outf,
             int ldc,
             const u16* __restrict__ W2, int ldw2, u16* __restrict__ outb2)
{
  __shared__ u16 smem[32768];
  u16* const Abase = smem;
  u16* const Bbase = smem + 16384;

  const int tid  = threadIdx.x;
  const int wave = tid >> 6, lane = tid & 63;
  const int wr = wave >> 1, wc = wave & 1;
  const int quad = lane >> 4, l16 = lane & 15;
  const int srow8 = lane >> 3;
  const int scolsw = ((lane & 7) ^ srow8) * 8;

  const int gx = gridDim.x;
  const int nwg = gx * gridDim.y;
  int flat = blockIdx.y * gx + blockIdx.x;
  if ((nwg & 7) == 0) { const int q = nwg >> 3; flat = (flat & 7) * q + (flat >> 3); }
  const int bx = flat % gx;
  const int by = flat / gx;

  const int row0 = by * 128;
  const bool isM = (MODE != 5) || (bx < 4);
  const int col0 = (MODE == 5 ? (bx & 3) : bx) * 128;
  const u16* Wp  = (MODE == 5 && !isM) ? W2  : W;
  const int ldwp = (MODE == 5 && !isM) ? ldw2 : ldw;

  f32x4 acc[4][4];
#pragma unroll
  for (int i = 0; i < 4; i++)
#pragma unroll
    for (int j = 0; j < 4; j++)
#pragma unroll
      for (int r = 0; r < 4; r++) acc[i][j][r] = 0.f;

  float4 rf[8];
  uint4  ra[4];

  auto stageA = [&](int kk0, u16* dst) {
#pragma unroll
    for (int i = 0; i < 4; i++) {
      const int chunk = wave * 4 + i;
      gl_lds16((const u16*)Av + (abase + (size_t)(row0 + chunk * 8 + srow8)) * lda + kk0 + scolsw,
               dst + chunk * 512 + lane * 8);
    }
  };
  auto stageB = [&](int kk0, u16* dst) {
#pragma unroll
    for (int i = 0; i < 4; i++) {
      const int chunk = wave * 4 + i;
      gl_lds16(Wp + (size_t)(col0 + chunk * 8 + srow8) * ldwp + kk0 + scolsw,
               dst + chunk * 512 + lane * 8);
    }
  };
  auto loadRF = [&](int kk0) {
#pragma unroll
    for (int i = 0; i < 4; i++) {
      const int idx = i * 256 + tid, sr = idx >> 3, sc = (idx & 7) * 8;
      const float* p = (const float*)Av + (abase + (size_t)(row0 + sr)) * lda + kk0 + sc;
      rf[2 * i]     = *(const float4*)p;
      rf[2 * i + 1] = *(const float4*)(p + 4);
    }
  };
  auto convRA = [&]() {
#pragma unroll
    for (int i = 0; i < 4; i++) {
      ra[i].x = pk2(rf[2 * i].x, rf[2 * i].y);
      ra[i].y = pk2(rf[2 * i].z, rf[2 * i].w);
      ra[i].z = pk2(rf[2 * i + 1].x, rf[2 * i + 1].y);
      ra[i].w = pk2(rf[2 * i + 1].z, rf[2 * i + 1].w);
    }
  };
  auto writeA = [&](u16* dst) {
#pragma unroll
    for (int i = 0; i < 4; i++) {
      const int idx = i * 256 + tid, sr = idx >> 3, cb = idx & 7;
      *(uint4*)(dst + sr * 64 + ((cb ^ (sr & 7)) << 3)) = ra[i];
    }
  };
  auto compute = [&](const u16* Ac, const u16* Bc) {
#pragma unroll
    for (int kk = 0; kk < 64; kk += 32) {
      const int cb0 = (kk >> 3) + quad;
      const int cbsw = ((cb0 ^ (l16 & 7)) << 3);
      bfrag af[4], bf[4];
#pragma unroll
      for (int mt = 0; mt < 4; mt++) {
        const int R = wr * 64 + mt * 16 + l16;
        af[mt] = *(const bfrag*)(Ac + R * 64 + cbsw);
      }
#pragma unroll
      for (int nt2 = 0; nt2 < 4; nt2++) {
        const int R = wc * 64 + nt2 * 16 + l16;
        bf[nt2] = *(const bfrag*)(Bc + R * 64 + cbsw);
      }
#pragma unroll
      for (int mt = 0; mt < 4; mt++)
#pragma unroll
        for (int nt2 = 0; nt2 < 4; nt2++)
          acc[mt][nt2] = __builtin_amdgcn_mfma_f32_16x16x32_bf16(af[mt], bf[nt2], acc[mt][nt2], 0, 0, 0);
    }
  };

  const int ntile = K >> 6;
  int cur = 0;

  if constexpr (A32) {
    loadRF(0); convRA(); writeA(Abase);
    stageB(0, Bbase);
    if (ntile > 1) loadRF(64);
  } else {
    stageA(0, Abase);
    stageB(0, Bbase);
  }
  __syncthreads();

  for (int t = 0; t < ntile; ++t) {
    const bool more = (t + 1 < ntile);
    u16* Ac = Abase + cur * 8192;
    u16* Bc = Bbase + cur * 8192;
    u16* An = Abase + (cur ^ 1) * 8192;
    u16* Bn = Bbase + (cur ^ 1) * 8192;
    if (more) {
      if constexpr (!A32) stageA((t + 1) << 6, An);
      stageB((t + 1) << 6, Bn);
      if constexpr (A32) {
        convRA(); writeA(An);
        if (t + 2 < ntile) loadRF((t + 2) << 6);
      }
    }
    compute(Ac, Bc);
    __syncthreads();
    cur ^= 1;
  }

  if constexpr (MODE == 2) {
#pragma unroll
    for (int mt = 0; mt < 4; mt++) {
#pragma unroll
      for (int r = 0; r < 4; r++) {
        const int rg = row0 + wr * 64 + mt * 16 + quad * 4 + r;
        float s = 0.f;
#pragma unroll
        for (int nt = 0; nt < 4; nt++) {
          const int cg = col0 + wc * 64 + nt * 16 + l16;
          float v = acc[mt][nt][r] + u2f(bias[cg]);
          v = fmaxf(v, 0.f);
          s += v * u2f(wlo[cg]);
        }
#pragma unroll
        for (int off = 1; off < 16; off <<= 1) s += __shfl_xor(s, off, 16);
        if (l16 == 0) atomicAdd(pred + rg, s);
      }
    }
  } else if constexpr (MODE == 3) {
#pragma unroll
    for (int mt = 0; mt < 4; mt++)
#pragma unroll
      for (int nt = 0; nt < 4; nt++)
#pragma unroll
        for (int r = 0; r < 4; r++) {
          const int rg = row0 + wr * 64 + mt * 16 + quad * 4 + r;
          const int cg = col0 + wc * 64 + nt * 16 + l16;
          outf[(size_t)rg * ldc + cg] = acc[mt][nt][r] + u2f(bias[cg]);
        }
  } else {
    u16* tile = smem;                    // 128 x 136
    u16* outp = (MODE == 5 && !isM) ? outb2 : outb;
    __syncthreads();
#pragma unroll
    for (int mt = 0; mt < 4; mt++)
#pragma unroll
      for (int nt = 0; nt < 4; nt++)
#pragma unroll
        for (int r = 0; r < 4; r++) {
          const int lrow = wr * 64 + mt * 16 + quad * 4 + r;
          const int lcol = wc * 64 + nt * 16 + l16;
          const int rg = row0 + lrow;
          const int cg = col0 + lcol;
          float v = acc[mt][nt][r];
          if (MODE == 0 || (MODE == 5 && isM)) {
            const size_t grow = abase + rg;
            const int urow = (int)(((grow >> 12) << 6) | (grow & 63));
            v += ubuf[(size_t)urow * 512 + cg];
            v = fmaxf(v, 0.f);
          } else if (MODE == 1 || MODE == 5) {
            v += u2f(bias[cg]);
            v = fmaxf(v, 0.f);
          } else {  // MODE 4
            v = sigm(pred[rg]) * v + u2f(bias[cg]);
            v = fmaxf(v, 0.f);
          }
          tile[lrow * 136 + lcol] = f2u(v);
        }
    __syncthreads();
    const int row = tid >> 1, half = tid & 1;
    const u16* src = tile + row * 136 + half * 64;
    u16* dst = outp + (size_t)(row0 + row) * ldc + col0 + half * 64;
#pragma unroll
    for (int j = 0; j < 8; j++)
      *(uint4*)(dst + j * 8) = *(const uint4*)(src + j * 8);
  }
}

__global__ void fill_kernel(float* __restrict__ p, const u16* __restrict__ val, int n) {
  int i = blockIdx.x * blockDim.x + threadIdx.x;
  if (i < n) p[i] = u2f(*val);
}

__global__ void adj_out_kernel(const float* __restrict__ r, float* __restrict__ out) {
  int i = blockIdx.x * 256 + threadIdx.x;            // (b,v,w)
  int b = i >> 12, v = (i >> 6) & 63, w = i & 63;
  out[i] = r[(b << 12) + (w << 6) + v];              // pred_adj[b,v,w] = r[b,w,v]
}

__global__ __launch_bounds__(512)
void msum_kernel(const float* __restrict__ r, const u16* __restrict__ M, u16* __restrict__ x) {
  const int bv = blockIdx.x;                          // b*64+v
  const int b = bv >> 6, v = bv & 63;
  __shared__ float s[64];
  if (threadIdx.x < 64) {
    const int w = threadIdx.x;
    s[w] = sigm(r[(b << 12) + (w << 6) + v]);
  }
  __syncthreads();
  const int m = threadIdx.x;                          // channel 0..511
  const u16* Mp = M + (((size_t)(b << 12) + (v << 6)) << 9) + m;
  float acc = 0.f;
#pragma unroll 8
  for (int w = 0; w < 64; w++) acc += s[w] * u2f(Mp[(size_t)w << 9]);
  x[(size_t)bv * 512 + m] = f2u(acc);
}

__global__ __launch_bounds__(256)
void gru_kernel(const float* __restrict__ gi, const float* __restrict__ gh,
                const u16* __restrict__ h, float* __restrict__ hn) {
  int i = blockIdx.x * 256 + threadIdx.x;             // 1024*512
  int row = i >> 9, d = i & 511;
  const float* gir = gi + (size_t)row * 1536;
  const float* ghr = gh + (size_t)row * 1536;
  float rr = sigm(gir[d] + ghr[d]);
  float z  = sigm(gir[512 + d] + ghr[512 + d]);
  float n  = tanhf(gir[1024 + d] + rr * ghr[1024 + d]);
  float hv = u2f(h[i]);
  hn[i] = (1.f - z) * n + z * hv;
}

__global__ __launch_bounds__(256)
void readout_kernel(const float* __restrict__ hn,
                    const u16* __restrict__ Wr1, const u16* __restrict__ br1,
                    const u16* __restrict__ Wr2, const u16* __restrict__ br2,
                    float* __restrict__ out) {
  const int row = blockIdx.x;
  __shared__ float hrow[512];
  for (int d = threadIdx.x; d < 512; d += 256) hrow[d] = hn[(size_t)row * 512 + d];
  __syncthreads();
  const int wave = threadIdx.x >> 6, lane = threadIdx.x & 63;
  for (int j = wave; j < 28; j += 4) {
    const u16* wrow;
    float bias;
    size_t off;
    if (j < 26) { wrow = Wr1 + (size_t)j * 512; bias = u2f(br1[j]); off = 65536 + (size_t)row * 26 + j; }
    else { int jj = j - 26; wrow = Wr2 + (size_t)jj * 512; bias = u2f(br2[jj]); off = 92160 + (size_t)row * 2 + jj; }
    float s = 0.f;
    for (int d = lane; d < 512; d += 64) s += hrow[d] * u2f(wrow[d]);
#pragma unroll
    for (int o = 32; o; o >>= 1) s += __shfl_down(s, o);
    if (lane == 0) out[off] = s + bias;
  }
}

extern "C" void kernel_launch(void* const* d_in, const int* in_sizes, int n_in,
                              void* d_out, int out_size, void* d_ws, size_t ws_size,
                              hipStream_t stream)
{
  (void)in_sizes; (void)n_in; (void)out_size;
  const void*  X  = d_in[0];                 // edge_features [16,64,64,512] fp32
  char* ws = (char*)d_ws;

  const bool big = (ws_size >= 158905344ULL);   // full-H1 fused path needs ~151.5 MiB

  // ---- workspace layouts ----
  u16 *Mb, *H1, *xb, *nfb, *Wmb, *bmb, *Wl1b, *bl1b, *Wl2b, *bl2b, *Wlob, *blob;
  u16 *Wihb, *bihb, *Whhb, *bhhb, *Wr1b, *br1b, *Wr2b, *br2b;
  float *pred1, *rbuf, *ubuf, *gi, *gh, *hn;
  if (big) {
    Mb    = (u16*)(ws);                         // 64 MB  M bf16 [65536,512]
    H1    = (u16*)(ws + 67108864);              // 64 MB  link hidden, full
    pred1 = (float*)(ws + 134217728);           // 256 KB
    rbuf  = (float*)(ws + 134479872);           // 256 KB
    ubuf  = (float*)(ws + 134742016);           // 2 MB
    xb    = (u16*)(ws + 136839168);             // 1 MB
    gi    = (float*)(ws + 137887744);           // 6 MB
    gh    = (float*)(ws + 144179200);           // 6 MB
    hn    = (float*)(ws + 150470656);           // 2 MB
    nfb   = (u16*)(ws + 152567808);
    Wmb   = (u16*)(ws + 153616384);
    bmb   = (u16*)(ws + 154664960);
    Wl1b  = (u16*)(ws + 154665984);
    bl1b  = (u16*)(ws + 155190272);
    Wl2b  = (u16*)(ws + 155191296);
    bl2b  = (u16*)(ws + 155715584);
    Wlob  = (u16*)(ws + 155716608);
    blob  = (u16*)(ws + 155717632);
    Wihb  = (u16*)(ws + 155718656);
    bihb  = (u16*)(ws + 157291520);
    Whhb  = (u16*)(ws + 157295616);
    bhhb  = (u16*)(ws + 158868480);
    Wr1b  = (u16*)(ws + 158872576);
    br1b  = (u16*)(ws + 158901248);
    Wr2b  = (u16*)(ws + 158902272);
    br2b  = (u16*)(ws + 158904320);
  } else {                                      // R4 known-good quartered layout
    Mb    = (u16*)(ws);
    H1    = (u16*)(ws + 67108864);
    pred1 = (float*)(ws + 83886080);
    rbuf  = (float*)(ws + 84148224);
    ubuf  = (float*)(ws + 84410368);
    xb    = (u16*)(ws + 86507520);
    gi    = (float*)(ws + 87556096);
    gh    = (float*)(ws + 93847552);
    hn    = (float*)(ws + 100139008);
    nfb   = (u16*)(ws + 102236416);
    Wmb   = (u16*)(ws + 103284992);
    bmb   = (u16*)(ws + 104333568);
    Wl1b  = (u16*)(ws + 104334592);
    bl1b  = (u16*)(ws + 104858880);
    Wl2b  = (u16*)(ws + 104859904);
    bl2b  = (u16*)(ws + 105384192);
    Wlob  = (u16*)(ws + 105385216);
    blob  = (u16*)(ws + 105386240);
    Wihb  = (u16*)(ws + 105387264);
    bihb  = (u16*)(ws + 106960128);
    Whhb  = (u16*)(ws + 106964224);
    bhhb  = (u16*)(ws + 108537088);
    Wr1b  = (u16*)(ws + 108541184);
    br1b  = (u16*)(ws + 108573952);
    Wr2b  = (u16*)(ws + 108574976);
    br2b  = (u16*)(ws + 108579072);
  }

  float* out = (float*)d_out;

  // batched weight conversion (1 launch)
  {
    CvtArgs ca;
    const int seg_in[NSEG]  = {1,4,5,6,7,8,9,10,11,12,13,14,15,16,17,18,19};
    u16* seg_dst[NSEG] = {nfb,Wmb,bmb,Wl1b,bl1b,Wl2b,bl2b,Wlob,blob,
                          Wihb,bihb,Whhb,bhhb,Wr1b,br1b,Wr2b,br2b};
    const int seg_n[NSEG] = {524288,524288,512,262144,512,262144,512,512,1,
                             786432,1536,786432,1536,13312,26,1024,2};
    int total = 0;
    for (int s = 0; s < NSEG; s++) {
      ca.src[s] = (const float*)d_in[seg_in[s]];
      ca.dst[s] = seg_dst[s];
      ca.cum[s] = total;
      total += seg_n[s];
    }
    ca.cum[NSEG] = total;
    cvt_multi<<<(total + 255) / 256, 256, 0, stream>>>(ca, total);
  }

  // u = nf @ Wm[:, :512]^T + bm  (fp32)
  gemm_bt<3, false><<<dim3(4, 8), 256, 0, stream>>>(nfb, 512, 0, Wmb, 1024, 512, bmb,
      nullptr, nullptr, nullptr, nullptr, ubuf, 512, nullptr, 0, nullptr);
  // pred1 & rbuf (contiguous 131072 floats) = blo
  fill_kernel<<<512, 256, 0, stream>>>(pred1, blob, 131072);

  if (big) {
    // fused: [Mb | H1] = relu(X @ [Wm_e | Wl1]^T + [u | bl1]), X read once
    gemm256<5, true><<<dim3(4, 256), 512, 0, stream>>>(X, 512, 0, Wmb + 512, 1024, 512,
        bl1b, ubuf, nullptr, nullptr, Mb, 512, Wl1b, 512, H1);
    // pred1 += sum relu(H1 @ Wl2^T + bl2) * Wlo
    gemm256<2, false><<<dim3(2, 256), 512, 0, stream>>>(H1, 512, 0, Wl2b, 512, 512, bl2b,
        nullptr, Wlob, pred1, nullptr, 512, nullptr, 0, nullptr);
    // H1 = relu(sigm(pred1) * M @ Wl1^T + bl1)
    gemm256<4, false><<<dim3(2, 256), 512, 0, stream>>>(Mb, 512, 0, Wl1b, 512, 512, bl1b,
        nullptr, nullptr, pred1, H1, 512, nullptr, 0, nullptr);
    gemm256<2, false><<<dim3(2, 256), 512, 0, stream>>>(H1, 512, 0, Wl2b, 512, 512, bl2b,
        nullptr, Wlob, rbuf, nullptr, 512, nullptr, 0, nullptr);
  } else {
    gemm_bt<0, true><<<dim3(4, 512), 256, 0, stream>>>(X, 512, 0, Wmb + 512, 1024, 512,
        nullptr, ubuf, nullptr, nullptr, Mb, nullptr, 512, nullptr, 0, nullptr);
    for (int q = 0; q < 4; q++) {
      const size_t ro = (size_t)q * 16384;
      gemm_bt<1, true><<<dim3(4, 128), 256, 0, stream>>>(X, 512, ro, Wl1b, 512, 512, bl1b,
          nullptr, nullptr, nullptr, H1, nullptr, 512, nullptr, 0, nullptr);
      gemm_bt<2, false><<<dim3(4, 128), 256, 0, stream>>>(H1, 512, 0, Wl2b, 512, 512, bl2b,
          nullptr, Wlob, pred1 + ro, nullptr, nullptr, 512, nullptr, 0, nullptr);
    }
    for (int q = 0; q < 4; q++) {
      const size_t ro = (size_t)q * 16384;
      gemm_bt<4, false><<<dim3(4, 128), 256, 0, stream>>>(Mb, 512, ro, Wl1b, 512, 512, bl1b,
          nullptr, nullptr, pred1 + ro, H1, nullptr, 512, nullptr, 0, nullptr);
      gemm_bt<2, false><<<dim3(4, 128), 256, 0, stream>>>(H1, 512, 0, Wl2b, 512, 512, bl2b,
          nullptr, Wlob, rbuf + ro, nullptr, nullptr, 512, nullptr, 0, nullptr);
    }
  }

  // pred_adj[b,v,w] = rbuf[b,w,v]
  adj_out_kernel<<<256, 256, 0, stream>>>(rbuf, out);
  // x[b,v,:] = sum_w sigmoid(rbuf[b,w,v]) * M[b,:,v,w]
  msum_kernel<<<1024, 512, 0, stream>>>(rbuf, Mb, xb);
  // GRU gates
  gemm_bt<3, false><<<dim3(12, 8), 256, 0, stream>>>(xb, 512, 0, Wihb, 512, 512, bihb,
      nullptr, nullptr, nullptr, nullptr, gi, 1536, nullptr, 0, nullptr);
  gemm_bt<3, false><<<dim3(12, 8), 256, 0, stream>>>(nfb, 512, 0, Whhb, 512, 512, bhhb,
      nullptr, nullptr, nullptr, nullptr, gh, 1536, nullptr, 0, nullptr);
  gru_kernel<<<2048, 256, 0, stream>>>(gi, gh, nfb, hn);
  readout_kernel<<<1024, 256, 0, stream>>>(hn, Wr1b, br1b, Wr2b, br2b, out);
}

// Round 4
// 619.954 us; speedup vs baseline: 1.1241x; 1.1241x over previous
//
#include <hip/hip_runtime.h>
#include <hip/hip_bf16.h>
#include <stdint.h>
#include <stddef.h>

// Inputs/outputs are fp32. Weights converted once to bf16 in ws; GEMMs run bf16
// MFMA with fp32 accumulate.
// R4 changes vs R3 (697 us):
//  - NEW gemm_p3 (T3+T4+T5): BM=128 BN=256 BK=32, 512 thr (8 waves 2Mx4N,
//    wave=64x64, acc=64 regs -> ~12 waves/CU vs R3's 8). A TRIPLE-buffered,
//    B double-buffered (56 KiB LDS). Counted s_waitcnt vmcnt(1|2) + raw
//    s_barrier -- vmcnt NEVER drains to 0 in the main loop (R1-R3 all did via
//    __syncthreads, exposing full load latency every K-step; m218: counted
//    vmcnt is +38-73%). A32: WRITEA(t+1) auto-waits rf issued a full iteration
//    earlier; LOADRF(t+2) after. setprio(1) around MFMA cluster (T5).
//  - Heavy dispatches (MODE5, 2xMODE2, MODE4) on gemm_p3; small GEMMs and the
//    !big fallback keep the proven gemm_bt.

using u16 = unsigned short;
using u32 = unsigned int;

__device__ __forceinline__ float u2f(u16 u) {
  union { unsigned i; float f; } c; c.i = ((unsigned)u) << 16; return c.f;
}
__device__ __forceinline__ u16 f2u(float f) {
  __hip_bfloat16 h = __float2bfloat16(f);          // RNE
  union { __hip_bfloat16 h; u16 u; } c; c.h = h; return c.u;
}
__device__ __forceinline__ u32 pk2(float lo, float hi) {
  __hip_bfloat162 h = __float22bfloat162_rn(make_float2(lo, hi));
  union { __hip_bfloat162 h; u32 u; } c; c.h = h; return c.u;
}
__device__ __forceinline__ float sigm(float x) { return 1.f / (1.f + expf(-x)); }

typedef __attribute__((ext_vector_type(8))) short bfrag;   // 8 bf16 = 4 VGPRs
typedef __attribute__((ext_vector_type(4))) float f32x4;

__device__ __forceinline__ void gl_lds16(const u16* g, u16* l) {
  __builtin_amdgcn_global_load_lds((const __attribute__((address_space(1))) void*)g,
                                   (__attribute__((address_space(3))) void*)l,
                                   16, 0, 0);
}

// ---- batched fp32 -> bf16 weight conversion (17 segments, 1 launch) ----
#define NSEG 17
struct CvtArgs {
  const float* src[NSEG];
  u16* dst[NSEG];
  int cum[NSEG + 1];
};
__global__ __launch_bounds__(256) void cvt_multi(CvtArgs a, int total) {
  int i = blockIdx.x * 256 + threadIdx.x;
  if (i >= total) return;
  int s = 0;
  while (s + 1 < NSEG && i >= a.cum[s + 1]) ++s;
  const int off = i - a.cum[s];
  a.dst[s][off] = f2u(a.src[s][off]);
}

// ============================================================================
// gemm_p3: BM=128, BN=256, BK=32 pipelined GEMM. C = epilogue(A @ W^T).
// A:[rows,K] fp32(A32) or bf16. W:[cols,K] bf16. 512 thr, 8 waves (2M x 4N).
// A 3-deep LDS (8KB each), B 2-deep (16KB each) = 56 KiB. Counted vmcnt.
// MODE 2: atomicAdd(pred[row], sum_col relu(acc+bias[col])*wlo[col])
// MODE 4: outb = bf16(relu(sigm(pred[row])*acc + bias[col]))
// MODE 5: bx<2 -> ubuf-add relu into outb; bx>=2 -> W2/bias relu into outb2
// ============================================================================
template <int MODE, bool A32>
__global__ __launch_bounds__(512, 2)
void gemm_p3(const void* __restrict__ Av, int lda, size_t abase,
             const u16* __restrict__ W, int ldw, int K,
             const u16* __restrict__ bias,
             const float* __restrict__ ubuf,
             const u16* __restrict__ wlo,
             float* __restrict__ pred,
             u16* __restrict__ outb, int ldc,
             const u16* __restrict__ W2, int ldw2, u16* __restrict__ outb2)
{
  __shared__ u16 smem[28672];                       // 56 KiB
  // A bufs: 3 x 4096 u16; B bufs: 2 x 8192 u16
  u16* const Ab0 = smem;
  u16* const Bb0 = smem + 12288;

  const int tid  = threadIdx.x;
  const int wave = tid >> 6, lane = tid & 63;
  const int wr = wave >> 2, wc = wave & 3;          // 2M x 4N
  const int quad = lane >> 4, l16 = lane & 15;

  // T1 bijective XCD swizzle
  const int gx = gridDim.x;
  const int nwg = gx * gridDim.y;
  int flat = blockIdx.y * gx + blockIdx.x;
  if ((nwg & 7) == 0) { const int q = nwg >> 3; flat = (flat & 7) * q + (flat >> 3); }
  const int bx = flat % gx;
  const int by = flat / gx;

  const int row0 = by * 128;
  const bool isM = (MODE != 5) || (bx < 2);
  const int col0 = (MODE == 5 ? (bx & 1) : bx) * 256;
  const u16* Wp  = (MODE == 5 && !isM) ? W2  : W;
  const int ldwp = (MODE == 5 && !isM) ? ldw2 : ldw;

  f32x4 acc[4][4];
#pragma unroll
  for (int i = 0; i < 4; i++)
#pragma unroll
    for (int j = 0; j < 4; j++)
#pragma unroll
      for (int r = 0; r < 4; r++) acc[i][j][r] = 0.f;

  // --- staging helpers (linear LDS dest, inverse-swizzled global source) ---
  auto stageA = [&](int k0, u16* Ab) {              // !A32: 1 chunk/thread
    const int c = tid, r = c >> 2;
    const int scb = (c & 3) ^ ((r >> 1) & 3);
    gl_lds16((const u16*)Av + (abase + (size_t)(row0 + r)) * lda + k0 + scb * 8,
             Ab + c * 8);
  };
  auto stageB = [&](int k0, u16* Bb) {              // 2 chunks/thread
#pragma unroll
    for (int p = 0; p < 2; p++) {
      const int c = p * 512 + tid, r = c >> 2;
      const int scb = (c & 3) ^ ((r >> 1) & 3);
      gl_lds16(Wp + (size_t)(col0 + r) * ldwp + k0 + scb * 8, Bb + c * 8);
    }
  };

  float4 rf0, rf1;                                  // A32 reg stage: 8 floats/thread
  auto loadRF = [&](int k0) {
    const float* p_ = (const float*)Av +
        (abase + (size_t)(row0 + (tid >> 2))) * lda + k0 + (tid & 3) * 8;
    rf0 = *(const float4*)p_;
    rf1 = *(const float4*)(p_ + 4);
  };
  auto writeA = [&](u16* Ab) {                      // swizzled ds_write_b128
    const int r = tid >> 2, cb = tid & 3;
    uint4 w;
    w.x = pk2(rf0.x, rf0.y); w.y = pk2(rf0.z, rf0.w);
    w.z = pk2(rf1.x, rf1.y); w.w = pk2(rf1.z, rf1.w);
    *(uint4*)(Ab + r * 32 + ((cb ^ ((r >> 1) & 3)) << 3)) = w;
  };

  auto compute = [&](const u16* Ab, const u16* Bb) {
    bfrag af[4], bf[4];
#pragma unroll
    for (int mt = 0; mt < 4; mt++) {
      const int R = wr * 64 + mt * 16 + l16;
      af[mt] = *(const bfrag*)(Ab + R * 32 + ((quad ^ ((R >> 1) & 3)) << 3));
    }
#pragma unroll
    for (int nt = 0; nt < 4; nt++) {
      const int R = wc * 64 + nt * 16 + l16;
      bf[nt] = *(const bfrag*)(Bb + R * 32 + ((quad ^ ((R >> 1) & 3)) << 3));
    }
    __builtin_amdgcn_s_setprio(1);
#pragma unroll
    for (int mt = 0; mt < 4; mt++)
#pragma unroll
      for (int nt = 0; nt < 4; nt++)
        acc[mt][nt] = __builtin_amdgcn_mfma_f32_16x16x32_bf16(af[mt], bf[nt], acc[mt][nt], 0, 0, 0);
    __builtin_amdgcn_s_setprio(0);
  };

  const int nt_ = K >> 5;                           // K-steps of 32

  if constexpr (!A32) {
    // prologue: A(0),B(0) + A(1) in flight
    stageA(0, Ab0);
    stageB(0, Bb0);
    if (nt_ > 1) {
      stageA(32, Ab0 + 4096);
      asm volatile("s_waitcnt vmcnt(1)" ::: "memory");   // A0,B0 done; A1 in flight
    } else {
      asm volatile("s_waitcnt vmcnt(0)" ::: "memory");
    }
    __builtin_amdgcn_s_barrier();

    for (int t = 0; t < nt_; ++t) {
      if (t + 1 < nt_) stageB((t + 1) << 5, Bb0 + ((t + 1) & 1) * 8192);
      if (t + 2 < nt_) stageA((t + 2) << 5, Ab0 + ((t + 2) % 3) * 4096);
      compute(Ab0 + (t % 3) * 4096, Bb0 + (t & 1) * 8192);
      if (t + 2 < nt_) { asm volatile("s_waitcnt vmcnt(1)" ::: "memory"); }
      else             { asm volatile("s_waitcnt vmcnt(0)" ::: "memory"); }
      __builtin_amdgcn_s_barrier();
    }
  } else {
    // A32: A 2-deep via reg stage (write t+1 while computing t)
    loadRF(0);
    writeA(Ab0);                                    // auto-waits rf(0)
    stageB(0, Bb0);
    if (nt_ > 1) {
      loadRF(32);                                   // rf(1) in flight
      asm volatile("s_waitcnt vmcnt(2) lgkmcnt(0)" ::: "memory");  // B0 done
    } else {
      asm volatile("s_waitcnt vmcnt(0) lgkmcnt(0)" ::: "memory");
    }
    __builtin_amdgcn_s_barrier();

    for (int t = 0; t < nt_; ++t) {
      if (t + 1 < nt_) {
        stageB((t + 1) << 5, Bb0 + ((t + 1) & 1) * 8192);
        writeA(Ab0 + ((t + 1) & 1) * 4096);         // auto-waits rf(t+1)
      }
      if (t + 2 < nt_) loadRF((t + 2) << 5);        // rf(t+2), crosses barrier
      compute(Ab0 + (t & 1) * 4096, Bb0 + (t & 1) * 8192);
      if (t + 2 < nt_) { asm volatile("s_waitcnt vmcnt(2) lgkmcnt(0)" ::: "memory"); }
      else             { asm volatile("s_waitcnt vmcnt(0) lgkmcnt(0)" ::: "memory"); }
      __builtin_amdgcn_s_barrier();
    }
  }

  // C/D layout (m89/m91): col = lane&15, row = quad*4 + reg
  if constexpr (MODE == 2) {
#pragma unroll
    for (int mt = 0; mt < 4; mt++) {
#pragma unroll
      for (int r = 0; r < 4; r++) {
        const int rg = row0 + wr * 64 + mt * 16 + quad * 4 + r;
        float s = 0.f;
#pragma unroll
        for (int nt = 0; nt < 4; nt++) {
          const int cg = col0 + wc * 64 + nt * 16 + l16;
          float v = acc[mt][nt][r] + u2f(bias[cg]);
          v = fmaxf(v, 0.f);
          s += v * u2f(wlo[cg]);
        }
#pragma unroll
        for (int off = 1; off < 16; off <<= 1) s += __shfl_xor(s, off, 16);
        if (l16 == 0) atomicAdd(pred + rg, s);
      }
    }
  } else {
    // bf16 out via LDS, two 64-row passes (tile 64 x 264 = 33 KiB)
    u16* outp = (MODE == 5 && !isM) ? outb2 : outb;
    u16* tile = smem;
#pragma unroll
    for (int p = 0; p < 2; p++) {
      __syncthreads();
      if (wr == p) {
#pragma unroll
        for (int mt = 0; mt < 4; mt++)
#pragma unroll
          for (int nt = 0; nt < 4; nt++)
#pragma unroll
            for (int r = 0; r < 4; r++) {
              const int rg = row0 + p * 64 + mt * 16 + quad * 4 + r;
              const int cg = col0 + wc * 64 + nt * 16 + l16;
              float v = acc[mt][nt][r];
              if (MODE == 5 && isM) {
                const size_t grow = (size_t)rg;     // abase==0 here
                const int urow = (int)(((grow >> 12) << 6) | (grow & 63));
                v += ubuf[(size_t)urow * 512 + cg];
                v = fmaxf(v, 0.f);
              } else if (MODE == 5) {
                v += u2f(bias[cg]);
                v = fmaxf(v, 0.f);
              } else {                              // MODE 4
                v = sigm(pred[rg]) * v + u2f(bias[cg]);
                v = fmaxf(v, 0.f);
              }
              const int lrow = mt * 16 + quad * 4 + r;
              tile[lrow * 264 + wc * 64 + nt * 16 + l16] = f2u(v);
            }
      }
      __syncthreads();
      const int row = tid >> 3, ch = tid & 7;       // 64 rows x 8 chunks(64B)
      const u16* src = tile + row * 264 + ch * 32;
      u16* dst = outp + (size_t)(row0 + p * 64 + row) * ldc + col0 + ch * 32;
#pragma unroll
      for (int j = 0; j < 4; j++)
        *(uint4*)(dst + j * 8) = *(const uint4*)(src + j * 8);
    }
  }
}

// ============================================================================
// 128x128-tile GEMM (R2-proven) — small GEMMs + !big fallback path.
// ============================================================================
template <int MODE, bool A32>
__global__ __launch_bounds__(256)
void gemm_bt(const void* __restrict__ Av, int lda, size_t abase,
             const u16* __restrict__ W, int ldw, int K,
             const u16* __restrict__ bias,
             const float* __restrict__ ubuf,
             const u16* __restrict__ wlo,
             float* __restrict__ pred,
             u16* __restrict__ outb,
             float* __restrict__ outf,
             int ldc,
             const u16* __restrict__ W2, int ldw2, u16* __restrict__ outb2)
{
  __shared__ u16 smem[32768];
  u16* const Abase = smem;
  u16* const Bbase = smem + 16384;

  const int tid  = threadIdx.x;
  const int wave = tid >> 6, lane = tid & 63;
  const int wr = wave >> 1, wc = wave & 1;
  const int quad = lane >> 4, l16 = lane & 15;
  const int srow8 = lane >> 3;
  const int scolsw = ((lane & 7) ^ srow8) * 8;

  const int gx = gridDim.x;
  const int nwg = gx * gridDim.y;
  int flat = blockIdx.y * gx + blockIdx.x;
  if ((nwg & 7) == 0) { const int q = nwg >> 3; flat = (flat & 7) * q + (flat >> 3); }
  const int bx = flat % gx;
  const int by = flat / gx;

  const int row0 = by * 128;
  const bool isM = (MODE != 5) || (bx < 4);
  const int col0 = (MODE == 5 ? (bx & 3) : bx) * 128;
  const u16* Wp  = (MODE == 5 && !isM) ? W2  : W;
  const int ldwp = (MODE == 5 && !isM) ? ldw2 : ldw;

  f32x4 acc[4][4];
#pragma unroll
  for (int i = 0; i < 4; i++)
#pragma unroll
    for (int j = 0; j < 4; j++)
#pragma unroll
      for (int r = 0; r < 4; r++) acc[i][j][r] = 0.f;

  float4 rf[8];
  uint4  ra[4];

  auto stageA = [&](int kk0, u16* dst) {
#pragma unroll
    for (int i = 0; i < 4; i++) {
      const int chunk = wave * 4 + i;
      gl_lds16((const u16*)Av + (abase + (size_t)(row0 + chunk * 8 + srow8)) * lda + kk0 + scolsw,
               dst + chunk * 512 + lane * 8);
    }
  };
  auto stageB = [&](int kk0, u16* dst) {
#pragma unroll
    for (int i = 0; i < 4; i++) {
      const int chunk = wave * 4 + i;
      gl_lds16(Wp + (size_t)(col0 + chunk * 8 + srow8) * ldwp + kk0 + scolsw,
               dst + chunk * 512 + lane * 8);
    }
  };
  auto loadRF = [&](int kk0) {
#pragma unroll
    for (int i = 0; i < 4; i++) {
      const int idx = i * 256 + tid, sr = idx >> 3, sc = (idx & 7) * 8;
      const float* p = (const float*)Av + (abase + (size_t)(row0 + sr)) * lda + kk0 + sc;
      rf[2 * i]     = *(const float4*)p;
      rf[2 * i + 1] = *(const float4*)(p + 4);
    }
  };
  auto convRA = [&]() {
#pragma unroll
    for (int i = 0; i < 4; i++) {
      ra[i].x = pk2(rf[2 * i].x, rf[2 * i].y);
      ra[i].y = pk2(rf[2 * i].z, rf[2 * i].w);
      ra[i].z = pk2(rf[2 * i + 1].x, rf[2 * i + 1].y);
      ra[i].w = pk2(rf[2 * i + 1].z, rf[2 * i + 1].w);
    }
  };
  auto writeA = [&](u16* dst) {
#pragma unroll
    for (int i = 0; i < 4; i++) {
      const int idx = i * 256 + tid, sr = idx >> 3, cb = idx & 7;
      *(uint4*)(dst + sr * 64 + ((cb ^ (sr & 7)) << 3)) = ra[i];
    }
  };
  auto compute = [&](const u16* Ac, const u16* Bc) {
#pragma unroll
    for (int kk = 0; kk < 64; kk += 32) {
      const int cb0 = (kk >> 3) + quad;
      const int cbsw = ((cb0 ^ (l16 & 7)) << 3);
      bfrag af[4], bf[4];
#pragma unroll
      for (int mt = 0; mt < 4; mt++) {
        const int R = wr * 64 + mt * 16 + l16;
        af[mt] = *(const bfrag*)(Ac + R * 64 + cbsw);
      }
#pragma unroll
      for (int nt2 = 0; nt2 < 4; nt2++) {
        const int R = wc * 64 + nt2 * 16 + l16;
        bf[nt2] = *(const bfrag*)(Bc + R * 64 + cbsw);
      }
#pragma unroll
      for (int mt = 0; mt < 4; mt++)
#pragma unroll
        for (int nt2 = 0; nt2 < 4; nt2++)
          acc[mt][nt2] = __builtin_amdgcn_mfma_f32_16x16x32_bf16(af[mt], bf[nt2], acc[mt][nt2], 0, 0, 0);
    }
  };

  const int ntile = K >> 6;
  int cur = 0;

  if constexpr (A32) {
    loadRF(0); convRA(); writeA(Abase);
    stageB(0, Bbase);
    if (ntile > 1) loadRF(64);
  } else {
    stageA(0, Abase);
    stageB(0, Bbase);
  }
  __syncthreads();

  for (int t = 0; t < ntile; ++t) {
    const bool more = (t + 1 < ntile);
    u16* Ac = Abase + cur * 8192;
    u16* Bc = Bbase + cur * 8192;
    u16* An = Abase + (cur ^ 1) * 8192;
    u16* Bn = Bbase + (cur ^ 1) * 8192;
    if (more) {
      if constexpr (!A32) stageA((t + 1) << 6, An);
      stageB((t + 1) << 6, Bn);
      if constexpr (A32) {
        convRA(); writeA(An);
        if (t + 2 < ntile) loadRF((t + 2) << 6);
      }
    }
    compute(Ac, Bc);
    __syncthreads();
    cur ^= 1;
  }

  if constexpr (MODE == 2) {
#pragma unroll
    for (int mt = 0; mt < 4; mt++) {
#pragma unroll
      for (int r = 0; r < 4; r++) {
        const int rg = row0 + wr * 64 + mt * 16 + quad * 4 + r;
        float s = 0.f;
#pragma unroll
        for (int nt = 0; nt < 4; nt++) {
          const int cg = col0 + wc * 64 + nt * 16 + l16;
          float v = acc[mt][nt][r] + u2f(bias[cg]);
          v = fmaxf(v, 0.f);
          s += v * u2f(wlo[cg]);
        }
#pragma unroll
        for (int off = 1; off < 16; off <<= 1) s += __shfl_xor(s, off, 16);
        if (l16 == 0) atomicAdd(pred + rg, s);
      }
    }
  } else if constexpr (MODE == 3) {
#pragma unroll
    for (int mt = 0; mt < 4; mt++)
#pragma unroll
      for (int nt = 0; nt < 4; nt++)
#pragma unroll
        for (int r = 0; r < 4; r++) {
          const int rg = row0 + wr * 64 + mt * 16 + quad * 4 + r;
          const int cg = col0 + wc * 64 + nt * 16 + l16;
          outf[(size_t)rg * ldc + cg] = acc[mt][nt][r] + u2f(bias[cg]);
        }
  } else {
    u16* tile = smem;                    // 128 x 136
    u16* outp = (MODE == 5 && !isM) ? outb2 : outb;
    __syncthreads();
#pragma unroll
    for (int mt = 0; mt < 4; mt++)
#pragma unroll
      for (int nt = 0; nt < 4; nt++)
#pragma unroll
        for (int r = 0; r < 4; r++) {
          const int lrow = wr * 64 + mt * 16 + quad * 4 + r;
          const int lcol = wc * 64 + nt * 16 + l16;
          const int rg = row0 + lrow;
          const int cg = col0 + lcol;
          float v = acc[mt][nt][r];
          if (MODE == 0 || (MODE == 5 && isM)) {
            const size_t grow = abase + rg;
            const int urow = (int)(((grow >> 12) << 6) | (grow & 63));
            v += ubuf[(size_t)urow * 512 + cg];
            v = fmaxf(v, 0.f);
          } else if (MODE == 1 || MODE == 5) {
            v += u2f(bias[cg]);
            v = fmaxf(v, 0.f);
          } else {  // MODE 4
            v = sigm(pred[rg]) * v + u2f(bias[cg]);
            v = fmaxf(v, 0.f);
          }
          tile[lrow * 136 + lcol] = f2u(v);
        }
    __syncthreads();
    const int row = tid >> 1, half = tid & 1;
    const u16* src = tile + row * 136 + half * 64;
    u16* dst = outp + (size_t)(row0 + row) * ldc + col0 + half * 64;
#pragma unroll
    for (int j = 0; j < 8; j++)
      *(uint4*)(dst + j * 8) = *(const uint4*)(src + j * 8);
  }
}

__global__ void fill_kernel(float* __restrict__ p, const u16* __restrict__ val, int n) {
  int i = blockIdx.x * blockDim.x + threadIdx.x;
  if (i < n) p[i] = u2f(*val);
}

__global__ void adj_out_kernel(const float* __restrict__ r, float* __restrict__ out) {
  int i = blockIdx.x * 256 + threadIdx.x;            // (b,v,w)
  int b = i >> 12, v = (i >> 6) & 63, w = i & 63;
  out[i] = r[(b << 12) + (w << 6) + v];              // pred_adj[b,v,w] = r[b,w,v]
}

__global__ __launch_bounds__(512)
void msum_kernel(const float* __restrict__ r, const u16* __restrict__ M, u16* __restrict__ x) {
  const int bv = blockIdx.x;                          // b*64+v
  const int b = bv >> 6, v = bv & 63;
  __shared__ float s[64];
  if (threadIdx.x < 64) {
    const int w = threadIdx.x;
    s[w] = sigm(r[(b << 12) + (w << 6) + v]);
  }
  __syncthreads();
  const int m = threadIdx.x;                          // channel 0..511
  const u16* Mp = M + (((size_t)(b << 12) + (v << 6)) << 9) + m;
  float acc = 0.f;
#pragma unroll 8
  for (int w = 0; w < 64; w++) acc += s[w] * u2f(Mp[(size_t)w << 9]);
  x[(size_t)bv * 512 + m] = f2u(acc);
}

__global__ __launch_bounds__(256)
void gru_kernel(const float* __restrict__ gi, const float* __restrict__ gh,
                const u16* __restrict__ h, float* __restrict__ hn) {
  int i = blockIdx.x * 256 + threadIdx.x;             // 1024*512
  int row = i >> 9, d = i & 511;
  const float* gir = gi + (size_t)row * 1536;
  const float* ghr = gh + (size_t)row * 1536;
  float rr = sigm(gir[d] + ghr[d]);
  float z  = sigm(gir[512 + d] + ghr[512 + d]);
  float n  = tanhf(gir[1024 + d] + rr * ghr[1024 + d]);
  float hv = u2f(h[i]);
  hn[i] = (1.f - z) * n + z * hv;
}

__global__ __launch_bounds__(256)
void readout_kernel(const float* __restrict__ hn,
                    const u16* __restrict__ Wr1, const u16* __restrict__ br1,
                    const u16* __restrict__ Wr2, const u16* __restrict__ br2,
                    float* __restrict__ out) {
  const int row = blockIdx.x;
  __shared__ float hrow[512];
  for (int d = threadIdx.x; d < 512; d += 256) hrow[d] = hn[(size_t)row * 512 + d];
  __syncthreads();
  const int wave = threadIdx.x >> 6, lane = threadIdx.x & 63;
  for (int j = wave; j < 28; j += 4) {
    const u16* wrow;
    float bias;
    size_t off;
    if (j < 26) { wrow = Wr1 + (size_t)j * 512; bias = u2f(br1[j]); off = 65536 + (size_t)row * 26 + j; }
    else { int jj = j - 26; wrow = Wr2 + (size_t)jj * 512; bias = u2f(br2[jj]); off = 92160 + (size_t)row * 2 + jj; }
    float s = 0.f;
    for (int d = lane; d < 512; d += 64) s += hrow[d] * u2f(wrow[d]);
#pragma unroll
    for (int o = 32; o; o >>= 1) s += __shfl_down(s, o);
    if (lane == 0) out[off] = s + bias;
  }
}

extern "C" void kernel_launch(void* const* d_in, const int* in_sizes, int n_in,
                              void* d_out, int out_size, void* d_ws, size_t ws_size,
                              hipStream_t stream)
{
  (void)in_sizes; (void)n_in; (void)out_size;
  const void*  X  = d_in[0];                 // edge_features [16,64,64,512] fp32
  char* ws = (char*)d_ws;

  const bool big = (ws_size >= 158905344ULL);   // full-H1 fused path needs ~151.5 MiB

  // ---- workspace layouts ----
  u16 *Mb, *H1, *xb, *nfb, *Wmb, *bmb, *Wl1b, *bl1b, *Wl2b, *bl2b, *Wlob, *blob;
  u16 *Wihb, *bihb, *Whhb, *bhhb, *Wr1b, *br1b, *Wr2b, *br2b;
  float *pred1, *rbuf, *ubuf, *gi, *gh, *hn;
  if (big) {
    Mb    = (u16*)(ws);                         // 64 MB  M bf16 [65536,512]
    H1    = (u16*)(ws + 67108864);              // 64 MB  link hidden, full
    pred1 = (float*)(ws + 134217728);           // 256 KB
    rbuf  = (float*)(ws + 134479872);           // 256 KB
    ubuf  = (float*)(ws + 134742016);           // 2 MB
    xb    = (u16*)(ws + 136839168);             // 1 MB
    gi    = (float*)(ws + 137887744);           // 6 MB
    gh    = (float*)(ws + 144179200);           // 6 MB
    hn    = (float*)(ws + 150470656);           // 2 MB
    nfb   = (u16*)(ws + 152567808);
    Wmb   = (u16*)(ws + 153616384);
    bmb   = (u16*)(ws + 154664960);
    Wl1b  = (u16*)(ws + 154665984);
    bl1b  = (u16*)(ws + 155190272);
    Wl2b  = (u16*)(ws + 155191296);
    bl2b  = (u16*)(ws + 155715584);
    Wlob  = (u16*)(ws + 155716608);
    blob  = (u16*)(ws + 155717632);
    Wihb  = (u16*)(ws + 155718656);
    bihb  = (u16*)(ws + 157291520);
    Whhb  = (u16*)(ws + 157295616);
    bhhb  = (u16*)(ws + 158868480);
    Wr1b  = (u16*)(ws + 158872576);
    br1b  = (u16*)(ws + 158901248);
    Wr2b  = (u16*)(ws + 158902272);
    br2b  = (u16*)(ws + 158904320);
  } else {                                      // quartered fallback layout
    Mb    = (u16*)(ws);
    H1    = (u16*)(ws + 67108864);
    pred1 = (float*)(ws + 83886080);
    rbuf  = (float*)(ws + 84148224);
    ubuf  = (float*)(ws + 84410368);
    xb    = (u16*)(ws + 86507520);
    gi    = (float*)(ws + 87556096);
    gh    = (float*)(ws + 93847552);
    hn    = (float*)(ws + 100139008);
    nfb   = (u16*)(ws + 102236416);
    Wmb   = (u16*)(ws + 103284992);
    bmb   = (u16*)(ws + 104333568);
    Wl1b  = (u16*)(ws + 104334592);
    bl1b  = (u16*)(ws + 104858880);
    Wl2b  = (u16*)(ws + 104859904);
    bl2b  = (u16*)(ws + 105384192);
    Wlob  = (u16*)(ws + 105385216);
    blob  = (u16*)(ws + 105386240);
    Wihb  = (u16*)(ws + 105387264);
    bihb  = (u16*)(ws + 106960128);
    Whhb  = (u16*)(ws + 106964224);
    bhhb  = (u16*)(ws + 108537088);
    Wr1b  = (u16*)(ws + 108541184);
    br1b  = (u16*)(ws + 108573952);
    Wr2b  = (u16*)(ws + 108574976);
    br2b  = (u16*)(ws + 108579072);
  }

  float* out = (float*)d_out;

  // batched weight conversion (1 launch)
  {
    CvtArgs ca;
    const int seg_in[NSEG]  = {1,4,5,6,7,8,9,10,11,12,13,14,15,16,17,18,19};
    u16* seg_dst[NSEG] = {nfb,Wmb,bmb,Wl1b,bl1b,Wl2b,bl2b,Wlob,blob,
                          Wihb,bihb,Whhb,bhhb,Wr1b,br1b,Wr2b,br2b};
    const int seg_n[NSEG] = {524288,524288,512,262144,512,262144,512,512,1,
                             786432,1536,786432,1536,13312,26,1024,2};
    int total = 0;
    for (int s = 0; s < NSEG; s++) {
      ca.src[s] = (const float*)d_in[seg_in[s]];
      ca.dst[s] = seg_dst[s];
      ca.cum[s] = total;
      total += seg_n[s];
    }
    ca.cum[NSEG] = total;
    cvt_multi<<<(total + 255) / 256, 256, 0, stream>>>(ca, total);
  }

  // u = nf @ Wm[:, :512]^T + bm  (fp32)
  gemm_bt<3, false><<<dim3(4, 8), 256, 0, stream>>>(nfb, 512, 0, Wmb, 1024, 512, bmb,
      nullptr, nullptr, nullptr, nullptr, ubuf, 512, nullptr, 0, nullptr);
  // pred1 & rbuf (contiguous 131072 floats) = blo
  fill_kernel<<<512, 256, 0, stream>>>(pred1, blob, 131072);

  if (big) {
    // fused: [Mb | H1] = relu(X @ [Wm_e | Wl1]^T + [u | bl1]), X read once/col-tile
    gemm_p3<5, true><<<dim3(4, 512), 512, 0, stream>>>(X, 512, 0, Wmb + 512, 1024, 512,
        bl1b, ubuf, nullptr, nullptr, Mb, 512, Wl1b, 512, H1);
    // pred1 += sum relu(H1 @ Wl2^T + bl2) * Wlo
    gemm_p3<2, false><<<dim3(2, 512), 512, 0, stream>>>(H1, 512, 0, Wl2b, 512, 512, bl2b,
        nullptr, Wlob, pred1, nullptr, 512, nullptr, 0, nullptr);
    // H1 = relu(sigm(pred1) * M @ Wl1^T + bl1)
    gemm_p3<4, false><<<dim3(2, 512), 512, 0, stream>>>(Mb, 512, 0, Wl1b, 512, 512, bl1b,
        nullptr, nullptr, pred1, H1, 512, nullptr, 0, nullptr);
    gemm_p3<2, false><<<dim3(2, 512), 512, 0, stream>>>(H1, 512, 0, Wl2b, 512, 512, bl2b,
        nullptr, Wlob, rbuf, nullptr, 512, nullptr, 0, nullptr);
  } else {
    gemm_bt<0, true><<<dim3(4, 512), 256, 0, stream>>>(X, 512, 0, Wmb + 512, 1024, 512,
        nullptr, ubuf, nullptr, nullptr, Mb, nullptr, 512, nullptr, 0, nullptr);
    for (int q = 0; q < 4; q++) {
      const size_t ro = (size_t)q * 16384;
      gemm_bt<1, true><<<dim3(4, 128), 256, 0, stream>>>(X, 512, ro, Wl1b, 512, 512, bl1b,
          nullptr, nullptr, nullptr, H1, nullptr, 512, nullptr, 0, nullptr);
      gemm_bt<2, false><<<dim3(4, 128), 256, 0, stream>>>(H1, 512, 0, Wl2b, 512, 512, bl2b,
          nullptr, Wlob, pred1 + ro, nullptr, nullptr, 512, nullptr, 0, nullptr);
    }
    for (int q = 0; q < 4; q++) {
      const size_t ro = (size_t)q * 16384;
      gemm_bt<4, false><<<dim3(4, 128), 256, 0, stream>>>(Mb, 512, ro, Wl1b, 512, 512, bl1b,
          nullptr, nullptr, pred1 + ro, H1, nullptr, 512, nullptr, 0, nullptr);
      gemm_bt<2, false><<<dim3(4, 128), 256, 0, stream>>>(H1, 512, 0, Wl2b, 512, 512, bl2b,
          nullptr, Wlob, rbuf + ro, nullptr, nullptr, 512, nullptr, 0, nullptr);
    }
  }

  // pred_adj[b,v,w] = rbuf[b,w,v]
  adj_out_kernel<<<256, 256, 0, stream>>>(rbuf, out);
  // x[b,v,:] = sum_w sigmoid(rbuf[b,w,v]) * M[b,:,v,w]
  msum_kernel<<<1024, 512, 0, stream>>>(rbuf, Mb, xb);
  // GRU gates
  gemm_bt<3, false><<<dim3(12, 8), 256, 0, stream>>>(xb, 512, 0, Wihb, 512, 512, bihb,
      nullptr, nullptr, nullptr, nullptr, gi, 1536, nullptr, 0, nullptr);
  gemm_bt<3, false><<<dim3(12, 8), 256, 0, stream>>>(nfb, 512, 0, Whhb, 512, 512, bhhb,
      nullptr, nullptr, nullptr, nullptr, gh, 1536, nullptr, 0, nullptr);
  gru_kernel<<<2048, 256, 0, stream>>>(gi, gh, nfb, hn);
  readout_kernel<<<1024, 256, 0, stream>>>(hn, Wr1b, br1b, Wr2b, br2b, out);
}